// Round 6
// baseline (278.023 us; speedup 1.0000x reference)
//
#include <hip/hip_runtime.h>

#define TT 256
#define II 30
#define HH 128
#define TB 16
#define AROW 168   // f16 elems per A-row (336B: 16B-aligned, 2-way-bank-free)

typedef _Float16 half8 __attribute__((ext_vector_type(8)));
typedef float f32x4 __attribute__((ext_vector_type(4)));

#if __has_builtin(__builtin_amdgcn_exp2f)
#define EXP2(x) __builtin_amdgcn_exp2f(x)
#else
#define EXP2(x) exp2f(x)
#endif
#define RCP(x) __builtin_amdgcn_rcpf(x)

#define L2E 1.44269504089f
#define TWO_L2E 2.88539008177f

// inputs pre-scaled by log2(e) (sig) / 2*log2(e) (tanh)
__device__ __forceinline__ float sig2(float a) {   // sigmoid(a/L2E)
  return RCP(1.0f + EXP2(-a));
}
__device__ __forceinline__ float tanh2(float a) {  // tanh(a/(2*L2E))
  return fmaf(-2.0f, RCP(1.0f + EXP2(a)), 1.0f);
}
__device__ __forceinline__ float tanh2s(float c) { // tanh(c), unscaled input
  return tanh2(c * TWO_L2E);
}

__device__ __forceinline__ void lstm_step(
    int t, const _Float16* __restrict__ Ar, _Float16* __restrict__ Aw,
    const half8 (&bf)[4][5], const float (&bias)[4], float (&c)[4],
    float& xw, const float* __restrict__ xp, bool stg, int sS, int iS,
    int col, int grp, int w)
{
  float xn = 0.0f;
  if (stg && (t + 2 < TT)) xn = xp[(size_t)(t + 2) * II];  // 2-deep prefetch

  half8 af[5];
  #pragma unroll
  for (int ks = 0; ks < 5; ++ks)
    af[ks] = *reinterpret_cast<const half8*>(&Ar[col * AROW + ks * 32 + grp * 8]);

  f32x4 a0 = {bias[0], bias[0], bias[0], bias[0]};
  f32x4 a1 = {bias[1], bias[1], bias[1], bias[1]};
  #pragma unroll
  for (int ks = 0; ks < 5; ++ks)
    a0 = __builtin_amdgcn_mfma_f32_16x16x32_f16(af[ks], bf[0][ks], a0, 0, 0, 0);
  #pragma unroll
  for (int ks = 0; ks < 5; ++ks)
    a1 = __builtin_amdgcn_mfma_f32_16x16x32_f16(af[ks], bf[1][ks], a1, 0, 0, 0);

  // i,f sigmoids (trans pipe) overlap g,o MFMA chains (matrix pipe)
  float ig[4], fg[4];
  #pragma unroll
  for (int r = 0; r < 4; ++r) { ig[r] = sig2(a0[r]); fg[r] = sig2(a1[r]); }

  f32x4 a2 = {bias[2], bias[2], bias[2], bias[2]};
  f32x4 a3 = {bias[3], bias[3], bias[3], bias[3]};
  #pragma unroll
  for (int ks = 0; ks < 5; ++ks)
    a2 = __builtin_amdgcn_mfma_f32_16x16x32_f16(af[ks], bf[2][ks], a2, 0, 0, 0);
  #pragma unroll
  for (int ks = 0; ks < 5; ++ks)
    a3 = __builtin_amdgcn_mfma_f32_16x16x32_f16(af[ks], bf[3][ks], a3, 0, 0, 0);

  #pragma unroll
  for (int r = 0; r < 4; ++r) {
    const float tg = tanh2(a2[r]);
    const float og = sig2(a3[r]);
    const float cn = fmaf(fg[r], c[r], ig[r] * tg);
    c[r] = cn;
    const float th = tanh2s(cn);
    Aw[(grp * 4 + r) * AROW + w * 16 + col] = (_Float16)(og * th);
  }

  if (stg && (t + 1 < TT)) Aw[sS * AROW + HH + iS] = (_Float16)xw;
  __syncthreads();
  xw = xn;
}

__global__ __launch_bounds__(512, 2)
void lstm_mfma(const float* __restrict__ x,
               const float* __restrict__ W_ih,
               const float* __restrict__ W_hh,
               const float* __restrict__ b_ih,
               const float* __restrict__ b_hh,
               const float* __restrict__ W0,
               const float* __restrict__ b0v,
               const float* __restrict__ W1,
               const float* __restrict__ b1v,
               float* __restrict__ out)
{
  __shared__ __align__(16) _Float16 Ab[2][TB * AROW];  // [h(128) | x(30) | pad]
  __shared__ float y0ls[TB * 132];

  const int tid = threadIdx.x;
  const int bbase = blockIdx.x * TB;
  const int w = tid >> 6;       // wave 0..7
  const int lane = tid & 63;
  const int col = lane & 15;
  const int grp = lane >> 4;

  // ---- B-fragments, pre-scaled for exp2-based gates ----
  half8 bf[4][5];
  float bias[4];
  #pragma unroll
  for (int g = 0; g < 4; ++g) {
    const float sc = (g == 2) ? TWO_L2E : L2E;
    const int n = g * 128 + w * 16 + col;
    #pragma unroll
    for (int ks = 0; ks < 4; ++ks) {
      const float4 p = *reinterpret_cast<const float4*>(W_hh + n * HH + ks * 32 + grp * 8);
      const float4 q = *reinterpret_cast<const float4*>(W_hh + n * HH + ks * 32 + grp * 8 + 4);
      bf[g][ks] = (half8){(_Float16)(p.x * sc), (_Float16)(p.y * sc),
                          (_Float16)(p.z * sc), (_Float16)(p.w * sc),
                          (_Float16)(q.x * sc), (_Float16)(q.y * sc),
                          (_Float16)(q.z * sc), (_Float16)(q.w * sc)};
    }
    {
      float v[8];
      #pragma unroll
      for (int j = 0; j < 8; ++j) {
        const int cc = grp * 8 + j;
        v[j] = (cc < II) ? W_ih[n * II + cc] * sc : 0.0f;
      }
      bf[g][4] = (half8){(_Float16)v[0], (_Float16)v[1], (_Float16)v[2], (_Float16)v[3],
                         (_Float16)v[4], (_Float16)v[5], (_Float16)v[6], (_Float16)v[7]};
    }
    bias[g] = (b_ih[n] + b_hh[n]) * sc;
  }

  // ---- x staging: 60 lanes/wave, 2 samples/wave ----
  const bool stg = (lane < 60);
  const int sS = w * 2 + (lane >= 30 ? 1 : 0);
  const int iS = lane % 30;
  const float* xp = x + (size_t)(bbase + sS) * (TT * II) + iS;
  float xa = 0.0f, xw = 0.0f;
  if (stg) { xa = xp[0]; xw = xp[II]; }   // t=0, t=1

  // ---- init LDS ----
  if (tid < 256) {
    const int s = tid >> 4, u8 = (tid & 15) * 8;
    *reinterpret_cast<half8*>(&Ab[0][s * AROW + u8]) = (half8){0,0,0,0,0,0,0,0};
  }
  if (tid < 32) {
    const int b = tid >> 4, s = tid & 15;
    Ab[b][s * AROW + 158] = (_Float16)0.0f;
    Ab[b][s * AROW + 159] = (_Float16)0.0f;
  }
  if (stg) Ab[0][sS * AROW + HH + iS] = (_Float16)xa;

  float c[4] = {0.0f, 0.0f, 0.0f, 0.0f};
  __syncthreads();

  // ================= recurrence (2x unrolled, static buffers) =================
  for (int t = 0; t < TT; t += 2) {
    lstm_step(t,     Ab[0], Ab[1], bf, bias, c, xw, xp, stg, sS, iS, col, grp, w);
    lstm_step(t + 1, Ab[1], Ab[0], bf, bias, c, xw, xp, stg, sS, iS, col, grp, w);
  }

  // ================= head =================
  if (tid < 256) {
    const int s = tid >> 4;
    const int n0 = (tid & 15) * 8;
    float acch[8];
    #pragma unroll
    for (int nj = 0; nj < 8; ++nj) acch[nj] = b0v[n0 + nj];
    #pragma unroll
    for (int kb = 0; kb < 16; ++kb) {
      const half8 hh = *reinterpret_cast<const half8*>(&Ab[0][s * AROW + kb * 8]);
      float hf[8];
      #pragma unroll
      for (int j = 0; j < 8; ++j) hf[j] = (float)hh[j];
      #pragma unroll
      for (int nj = 0; nj < 8; ++nj) {
        const float4 w0 = *reinterpret_cast<const float4*>(W0 + (n0 + nj) * HH + kb * 8);
        const float4 w1 = *reinterpret_cast<const float4*>(W0 + (n0 + nj) * HH + kb * 8 + 4);
        acch[nj] = fmaf(hf[0], w0.x, fmaf(hf[1], w0.y, fmaf(hf[2], w0.z, fmaf(hf[3], w0.w,
                   fmaf(hf[4], w1.x, fmaf(hf[5], w1.y, fmaf(hf[6], w1.z, fmaf(hf[7], w1.w,
                        acch[nj]))))))));
      }
    }
    #pragma unroll
    for (int nj = 0; nj < 8; ++nj)
      y0ls[s * 132 + n0 + nj] = fmaxf(acch[nj], 0.0f);
  }
  __syncthreads();

  if (tid < TB * 11) {
    const int s = tid / 11;
    const int oo = tid % 11;
    float acc1 = b1v[oo];
    const float4* y4 = reinterpret_cast<const float4*>(y0ls + s * 132);
    const float4* w4 = reinterpret_cast<const float4*>(W1 + oo * HH);
    #pragma unroll 8
    for (int k4 = 0; k4 < 32; ++k4) {
      const float4 yv = y4[k4];
      const float4 wv4 = w4[k4];
      acc1 = fmaf(yv.x, wv4.x, fmaf(yv.y, wv4.y, fmaf(yv.z, wv4.z, fmaf(yv.w, wv4.w, acc1))));
    }
    out[(size_t)(bbase + s) * 11 + oo] = acc1;
  }
}

extern "C" void kernel_launch(void* const* d_in, const int* in_sizes, int n_in,
                              void* d_out, int out_size, void* d_ws, size_t ws_size,
                              hipStream_t stream) {
  const float* x    = (const float*)d_in[0];
  const float* W_ih = (const float*)d_in[1];
  const float* W_hh = (const float*)d_in[2];
  const float* b_ih = (const float*)d_in[3];
  const float* b_hh = (const float*)d_in[4];
  const float* W0   = (const float*)d_in[5];
  const float* b0   = (const float*)d_in[6];
  const float* W1   = (const float*)d_in[7];
  const float* b1   = (const float*)d_in[8];
  float* out = (float*)d_out;
  lstm_mfma<<<256, 512, 0, stream>>>(x, W_ih, W_hh, b_ih, b_hh, W0, b0, W1, b1, out);
}

// Round 8
// 234.542 us; speedup vs baseline: 1.1854x; 1.1854x over previous
//
#include <hip/hip_runtime.h>

#define TT 256
#define II 30
#define HH 128
#define TB 16
#define HROWF 136      // f16 stride for h panel rows (272B = 17*16B)
#define XROWF 40       // f16 stride for x panel rows (80B = 5*16B)
#define XTT 16         // timesteps per staged window
#define XPANEL (XTT * TB * XROWF)   // 10240 f16 per buffer

typedef _Float16 half8 __attribute__((ext_vector_type(8)));
typedef _Float16 half2v __attribute__((ext_vector_type(2)));
typedef float f32x4 __attribute__((ext_vector_type(4)));

#if __has_builtin(__builtin_amdgcn_exp2f)
#define EXP2(x) __builtin_amdgcn_exp2f(x)
#else
#define EXP2(x) exp2f(x)
#endif
#define RCP(x) __builtin_amdgcn_rcpf(x)

#define L2E 1.44269504089f
#define TWO_L2E 2.88539008177f

__device__ __forceinline__ float sig2(float a) {   // sigmoid(a/L2E)
  return RCP(1.0f + EXP2(-a));
}
__device__ __forceinline__ float tanh2(float a) {  // tanh(a/(2*L2E))
  return fmaf(-2.0f, RCP(1.0f + EXP2(a)), 1.0f);
}
__device__ __forceinline__ float tanh2s(float c) { // tanh(c)
  return tanh2(c * TWO_L2E);
}

__global__ __launch_bounds__(512, 2)
void lstm_mfma(const float* __restrict__ x,
               const float* __restrict__ W_ih,
               const float* __restrict__ W_hh,
               const float* __restrict__ b_ih,
               const float* __restrict__ b_hh,
               const float* __restrict__ W0,
               const float* __restrict__ b0v,
               const float* __restrict__ W1,
               const float* __restrict__ b1v,
               float* __restrict__ out)
{
  __shared__ __align__(16) _Float16 Hb[2][TB * HROWF];
  __shared__ __align__(16) _Float16 Xp[2][XPANEL];
  __shared__ float y0ls[TB * 132];

  const int tid = threadIdx.x;
  const int bbase = blockIdx.x * TB;
  const int wv = tid >> 6;      // wave 0..7
  const int lane = tid & 63;
  const int col = lane & 15;    // MFMA A-row (sample) / B-col (unit)
  const int grp = lane >> 4;    // k-slot group

  // ---- B-fragments (pre-scaled for exp2 gates); wave wv owns units wv*16+col,
  // lane holds i,f,g,o of the SAME unit -> gate math lane-local ----
  half8 bf[4][5];
  float bias[4];
  #pragma unroll
  for (int g = 0; g < 4; ++g) {
    const float sc = (g == 2) ? TWO_L2E : L2E;
    const int n = g * 128 + wv * 16 + col;
    #pragma unroll
    for (int ks = 0; ks < 4; ++ks) {
      const float4 p = *reinterpret_cast<const float4*>(W_hh + n * HH + ks * 32 + grp * 8);
      const float4 q = *reinterpret_cast<const float4*>(W_hh + n * HH + ks * 32 + grp * 8 + 4);
      bf[g][ks] = (half8){(_Float16)(p.x * sc), (_Float16)(p.y * sc),
                          (_Float16)(p.z * sc), (_Float16)(p.w * sc),
                          (_Float16)(q.x * sc), (_Float16)(q.y * sc),
                          (_Float16)(q.z * sc), (_Float16)(q.w * sc)};
    }
    {
      float v[8];
      #pragma unroll
      for (int j = 0; j < 8; ++j) {
        const int cc = grp * 8 + j;
        v[j] = (cc < II) ? W_ih[n * II + cc] * sc : 0.0f;
      }
      bf[g][4] = (half8){(_Float16)v[0], (_Float16)v[1], (_Float16)v[2], (_Float16)v[3],
                         (_Float16)v[4], (_Float16)v[5], (_Float16)v[6], (_Float16)v[7]};
    }
    bias[g] = (b_ih[n] + b_hh[n]) * sc;
  }

  // ---- x stager thread constants: 480 threads, 16 consecutive floats each ----
  const bool stg = (tid < 480);
  const int sS = stg ? (tid / 30) : 15;
  const int qS = tid % 30;
  const int g0 = qS * 16;
  const int tt0 = g0 / 30;       // starting timestep within window
  const int i00 = g0 % 30;       // starting elem within timestep
  const float* wbase = x + (size_t)(bbase + sS) * (TT * II);

  float4 xr0, xr1, xr2, xr3;
  auto xload = [&](int win) {
    if (!stg) return;
    const float* p = wbase + win * (XTT * II) + g0;   // 16B-aligned
    xr0 = *reinterpret_cast<const float4*>(p);
    xr1 = *reinterpret_cast<const float4*>(p + 4);
    xr2 = *reinterpret_cast<const float4*>(p + 8);
    xr3 = *reinterpret_cast<const float4*>(p + 12);
  };
  auto xwrite = [&](int dstb) {
    if (!stg) return;
    _Float16* d = &Xp[dstb][0];
    const float vv[16] = {xr0.x, xr0.y, xr0.z, xr0.w, xr1.x, xr1.y, xr1.z, xr1.w,
                          xr2.x, xr2.y, xr2.z, xr2.w, xr3.x, xr3.y, xr3.z, xr3.w};
    int tt = tt0, i = i00;
    #pragma unroll
    for (int j = 0; j < 16; ++j) {
      d[tt * (TB * XROWF) + sS * XROWF + i] = (_Float16)vv[j];
      ++i;
      if (i == II) { i = 0; ++tt; }
    }
  };

  // ---- init LDS: zero h(buf0); zero x-panel pad cols 30,31 (both bufs) ----
  if (tid < 256) {
    const int s = tid >> 4, u8 = (tid & 15) * 8;
    *reinterpret_cast<half8*>(&Hb[0][s * HROWF + u8]) = (half8){0,0,0,0,0,0,0,0};
  }
  {
    const int pb = tid >> 8, rr = tid & 255;
    const int tt = rr >> 4, s = rr & 15;
    *reinterpret_cast<half2v*>(&Xp[pb][tt * (TB * XROWF) + s * XROWF + II]) = (half2v){0, 0};
  }

  float c[4] = {0.0f, 0.0f, 0.0f, 0.0f};

  // stage window 0
  xload(0);
  xwrite(0);
  __syncthreads();

  auto step = [&](int tt_idx, const _Float16* Ar, _Float16* Aw, const _Float16* Xr) {
    half8 af[5];
    #pragma unroll
    for (int ks = 0; ks < 4; ++ks)
      af[ks] = *reinterpret_cast<const half8*>(&Ar[col * HROWF + ks * 32 + grp * 8]);
    af[4] = *reinterpret_cast<const half8*>(&Xr[tt_idx * (TB * XROWF) + col * XROWF + grp * 8]);

    f32x4 a0 = {bias[0], bias[0], bias[0], bias[0]};
    f32x4 a1 = {bias[1], bias[1], bias[1], bias[1]};
    #pragma unroll
    for (int ks = 0; ks < 5; ++ks)
      a0 = __builtin_amdgcn_mfma_f32_16x16x32_f16(af[ks], bf[0][ks], a0, 0, 0, 0);
    #pragma unroll
    for (int ks = 0; ks < 5; ++ks)
      a1 = __builtin_amdgcn_mfma_f32_16x16x32_f16(af[ks], bf[1][ks], a1, 0, 0, 0);

    float ig[4], fg[4];
    #pragma unroll
    for (int r = 0; r < 4; ++r) { ig[r] = sig2(a0[r]); fg[r] = sig2(a1[r]); }

    f32x4 a2 = {bias[2], bias[2], bias[2], bias[2]};
    f32x4 a3 = {bias[3], bias[3], bias[3], bias[3]};
    #pragma unroll
    for (int ks = 0; ks < 5; ++ks)
      a2 = __builtin_amdgcn_mfma_f32_16x16x32_f16(af[ks], bf[2][ks], a2, 0, 0, 0);
    #pragma unroll
    for (int ks = 0; ks < 5; ++ks)
      a3 = __builtin_amdgcn_mfma_f32_16x16x32_f16(af[ks], bf[3][ks], a3, 0, 0, 0);

    #pragma unroll
    for (int r = 0; r < 4; ++r) {
      const float tg = tanh2(a2[r]);
      const float og = sig2(a3[r]);
      const float cn = fmaf(fg[r], c[r], ig[r] * tg);
      c[r] = cn;
      Aw[(grp * 4 + r) * HROWF + wv * 16 + col] = (_Float16)(og * tanh2s(cn));
    }
    __syncthreads();
  };

  // ================= recurrence: 16 windows x 16 steps =================
  for (int win = 0; win < 16; ++win) {
    const _Float16* Xr = Xp[win & 1];
    if (win + 1 < 16) xload(win + 1);          // in-flight across ~1 step, drained once
    for (int k = 0; k < 8; k += 2) {
      step(k,     Hb[0], Hb[1], Xr);
      step(k + 1, Hb[1], Hb[0], Xr);
    }
    if (win + 1 < 16) xwrite((win + 1) & 1);   // target buffer unread this window
    for (int k = 8; k < 16; k += 2) {
      step(k,     Hb[0], Hb[1], Xr);
      step(k + 1, Hb[1], Hb[0], Xr);
    }
  }

  // ================= head =================
  if (tid < 256) {
    const int s = tid >> 4;
    const int n0 = (tid & 15) * 8;
    float acch[8];
    #pragma unroll
    for (int nj = 0; nj < 8; ++nj) acch[nj] = b0v[n0 + nj];
    #pragma unroll
    for (int kb = 0; kb < 16; ++kb) {
      const half8 hh = *reinterpret_cast<const half8*>(&Hb[0][s * HROWF + kb * 8]);
      float hf[8];
      #pragma unroll
      for (int j = 0; j < 8; ++j) hf[j] = (float)hh[j];
      #pragma unroll
      for (int nj = 0; nj < 8; ++nj) {
        const float4 w0 = *reinterpret_cast<const float4*>(W0 + (n0 + nj) * HH + kb * 8);
        const float4 w1 = *reinterpret_cast<const float4*>(W0 + (n0 + nj) * HH + kb * 8 + 4);
        acch[nj] = fmaf(hf[0], w0.x, fmaf(hf[1], w0.y, fmaf(hf[2], w0.z, fmaf(hf[3], w0.w,
                   fmaf(hf[4], w1.x, fmaf(hf[5], w1.y, fmaf(hf[6], w1.z, fmaf(hf[7], w1.w,
                        acch[nj]))))))));
      }
    }
    #pragma unroll
    for (int nj = 0; nj < 8; ++nj)
      y0ls[s * 132 + n0 + nj] = fmaxf(acch[nj], 0.0f);
  }
  __syncthreads();

  if (tid < TB * 11) {
    const int s = tid / 11;
    const int oo = tid % 11;
    float acc1 = b1v[oo];
    const float4* y4 = reinterpret_cast<const float4*>(y0ls + s * 132);
    const float4* w4 = reinterpret_cast<const float4*>(W1 + oo * HH);
    #pragma unroll 8
    for (int k4 = 0; k4 < 32; ++k4) {
      const float4 yv = y4[k4];
      const float4 wv4 = w4[k4];
      acc1 = fmaf(yv.x, wv4.x, fmaf(yv.y, wv4.y, fmaf(yv.z, wv4.z, fmaf(yv.w, wv4.w, acc1))));
    }
    out[(size_t)(bbase + s) * 11 + oo] = acc1;
  }
}

extern "C" void kernel_launch(void* const* d_in, const int* in_sizes, int n_in,
                              void* d_out, int out_size, void* d_ws, size_t ws_size,
                              hipStream_t stream) {
  const float* x    = (const float*)d_in[0];
  const float* W_ih = (const float*)d_in[1];
  const float* W_hh = (const float*)d_in[2];
  const float* b_ih = (const float*)d_in[3];
  const float* b_hh = (const float*)d_in[4];
  const float* W0   = (const float*)d_in[5];
  const float* b0   = (const float*)d_in[6];
  const float* W1   = (const float*)d_in[7];
  const float* b1   = (const float*)d_in[8];
  float* out = (float*)d_out;
  lstm_mfma<<<256, 512, 0, stream>>>(x, W_ih, W_hh, b_ih, b_hh, W0, b0, W1, b1, out);
}